// Round 6
// baseline (832.134 us; speedup 1.0000x reference)
//
#include <hip/hip_runtime.h>

typedef _Float16 f16;
typedef __attribute__((ext_vector_type(8))) _Float16 f16x8;
typedef __attribute__((ext_vector_type(4))) _Float16 f16x4;
typedef __attribute__((ext_vector_type(4))) float f32x4;

#define BATCH 16
#define NSEQ  2048
#define DDIM  300
#define DPK   328   // padded row length (f16) for row-major Xf/Yf (zeros in [300,328))
#define DPV   304   // padded d-rows for transposed XT/YT (zeros in [300,304))
#define NTP   2056  // padded q-cols for transposed copies (zeros in [2048,2056))
#define XF_ELEMS (BATCH*NSEQ*DPK)
#define XT_ELEMS (BATCH*DPV*NTP)

__device__ __forceinline__ void gl_lds16(const void* g, void* l) {
  __builtin_amdgcn_global_load_lds((const __attribute__((address_space(1))) unsigned int*)g,
                                   (__attribute__((address_space(3))) unsigned int*)l, 16, 0, 0);
}

// ---------------------------------------------------------------------------
// Preprocess: X,Y f32 -> f16 row-major (padded) + f16 transposed (padded)
// ---------------------------------------------------------------------------
__global__ __launch_bounds__(256) void prep_kernel(const float* __restrict__ X,
                                                   const float* __restrict__ Y,
                                                   f16* __restrict__ Xf, f16* __restrict__ Yf,
                                                   f16* __restrict__ XT, f16* __restrict__ YT) {
  __shared__ float tile[32][33];
  int bz   = blockIdx.z;            // 0..31 = tensor*16 + b
  int tsel = bz >> 4, b = bz & 15;
  const float* src = tsel ? Y : X;
  f16* dF = tsel ? Yf : Xf;
  f16* dT = tsel ? YT : XT;
  int d0 = blockIdx.y * 32;
  int q0 = blockIdx.x * 32;
  int tid = threadIdx.x;
  int c = tid & 31, rr = tid >> 5;

  #pragma unroll
  for (int i = 0; i < 4; ++i) {
    int qr = rr + i * 8;
    int q = q0 + qr, d = d0 + c;
    float v = 0.f;
    if (q < NSEQ && d < DDIM) v = src[(size_t)b * NSEQ * DDIM + (size_t)q * DDIM + d];
    tile[c][qr] = v;
    if (q < NSEQ && d < DPK) dF[(size_t)b * NSEQ * DPK + (size_t)q * DPK + d] = (f16)v;
  }
  __syncthreads();
  #pragma unroll
  for (int i = 0; i < 4; ++i) {
    int dr = rr + i * 8;
    int d = d0 + dr, q = q0 + c;
    if (d < DPV && q < NTP) dT[(size_t)b * DPV * NTP + (size_t)d * NTP + q] = (f16)tile[dr][c];
  }
}

// ---------------------------------------------------------------------------
// Flash attention v6: ONE 1024-thread block per CU. 16 waves = 8 q-groups x 2
// members, QBLK=256, KV tile 32. Member: QK^T for qg's 32 q over its 16-kv
// half; PV d-split (member0 d<160, member1 d>=160). K,V double-buffered;
// stage(t+1) issued right after QK^T (WAR-safe: protected by B3 of t-1).
// Per tile: QK -> stage -> B1(lgkm: max exch) -> exp/P -> B2(lgkm) -> PV
// -> B3(lgkm+vmcnt(0)). LDS 113 KB (<128 usable) -> 16 waves/CU, 4/SIMD.
// VGPR must stay <=128 for 16 waves (R5 measured 108). Grid 256 = 1/CU.
// ---------------------------------------------------------------------------
__global__ __launch_bounds__(1024) void attn_kernel(const f16* __restrict__ Xf,
                                                    const f16* __restrict__ Yf,
                                                    const f16* __restrict__ XT,
                                                    const f16* __restrict__ YT,
                                                    float* __restrict__ out) {
  __shared__ __align__(16) f16 Ksh[2][32][DPK];   // 41984 B (656 B rows)
  __shared__ __align__(16) f16 VTsh[2][DPV][40];  // 48640 B (80 B rows)
  __shared__ __align__(16) f16 Psh[8][32][40];    // 20480 B per-qg P
  __shared__ float2 Mx[8][2][16];                 //  2048 B max/lsum exchange
                                                  // total 113152 B

  int idx = blockIdx.x;
  int swz = (idx & 7) * 32 + (idx >> 3);          // 256 % 8 == 0: bijective XCD chunking
  int qt  = swz & 7;
  int b   = (swz >> 3) & 15;
  int dir = swz >> 7;

  const f16* Qsrc = dir ? Yf : Xf;
  const f16* Ksrc = dir ? Xf : Yf;
  const f16* Vts  = dir ? XT : YT;   // V^T source [DPV][NTP]

  const size_t bq = (size_t)b * NSEQ * DPK;
  const size_t bt = (size_t)b * DPV * NTP;

  int tid = threadIdx.x;
  int lane = tid & 63, wid = tid >> 6;
  int qg = wid >> 1, mem = wid & 1;
  int l15 = lane & 15, g = lane >> 4;
  int qbase = qt * 256 + qg * 32;     // q-group's 32 rows (shared by both members)

  // Q fragments (both members hold qg's 32 q): lane = Q[q=qi*16+l15][ks*32+g*8+j]
  f16x8 qf[2][10];
  #pragma unroll
  for (int qi = 0; qi < 2; ++qi) {
    const f16* qrow = Qsrc + bq + (size_t)(qbase + qi * 16 + l15) * DPK + g * 8;
    #pragma unroll
    for (int ks = 0; ks < 10; ++ks) qf[qi][ks] = *(const f16x8*)(qrow + ks * 32);
  }

  const int dtoff = mem ? 10 : 0;     // PV d-tiles: member0 d 0..159, member1 160..303
  const int ndt   = mem ? 9 : 10;

  f32x4 O[10][2];
  #pragma unroll
  for (int dt = 0; dt < 10; ++dt) {
    O[dt][0] = (f32x4){0.f, 0.f, 0.f, 0.f};
    O[dt][1] = (f32x4){0.f, 0.f, 0.f, 0.f};
  }
  float m0 = -3.0e38f, m1 = -3.0e38f, l0 = 0.f, l1 = 0.f;

  const char* gK0 = (const char*)(Ksrc + bq);
  const char* gV0 = (const char*)(Vts + bt);

  auto stageK = [&](int tt, int buf) {
    const char* gK = gK0 + (size_t)tt * (32 * DPK * 2);
    char* lK = (char*)&Ksh[buf][0][0];
    #pragma unroll
    for (int i = 0; i < 2; ++i) {          // 1312 chunks of 16 B
      int c = i * 1024 + tid;
      if (c < 1312) gl_lds16(gK + c * 16, lK + c * 16);
    }
  };
  auto stageV = [&](int tt, int buf) {
    const char* gV = gV0 + (size_t)tt * 64;
    char* lV = (char*)&VTsh[buf][0][0];
    #pragma unroll
    for (int i = 0; i < 2; ++i) {          // 304 rows x 5 slots (64 B data + 16 B pad read)
      int c = i * 1024 + tid;
      if (c < 1520) {
        int row = c / 5, slot = c - row * 5;
        gl_lds16(gV + (size_t)row * (NTP * 2) + slot * 16, lV + c * 16);
      }
    }
  };

  stageK(0, 0);
  stageV(0, 0);
  asm volatile("s_waitcnt vmcnt(0)" ::: "memory");
  __builtin_amdgcn_s_barrier();
  __builtin_amdgcn_sched_barrier(0);

  #pragma unroll 1
  for (int t = 0; t < 64; ++t) {
    int cur = t & 1;

    // ---- QK^T: S^T[own 16-kv half][qg's 32 q]
    f32x4 S0 = (f32x4){0.f,0.f,0.f,0.f}, S1 = (f32x4){0.f,0.f,0.f,0.f};
    __builtin_amdgcn_s_setprio(1);
    #pragma unroll
    for (int ks = 0; ks < 10; ++ks) {
      f16x8 a = *(const f16x8*)&Ksh[cur][mem * 16 + l15][ks * 32 + g * 8];
      S0 = __builtin_amdgcn_mfma_f32_16x16x32_f16(a, qf[0][ks], S0, 0, 0, 0);
      S1 = __builtin_amdgcn_mfma_f32_16x16x32_f16(a, qf[1][ks], S1, 0, 0, 0);
    }
    __builtin_amdgcn_s_setprio(0);

    // ---- stage t+1 early (WAR-safe: buf^1 reads finished before B3 of t-1);
    //      loads get the whole softmax+PV window to land before B3's vmcnt(0).
    if (t < 63) { stageK(t + 1, cur ^ 1); stageV(t + 1, cur ^ 1); }

    // ---- partial max over own 16 kv (per q-col = l15, per qi)
    float p0 = fmaxf(fmaxf(S0[0], S0[1]), fmaxf(S0[2], S0[3]));
    float p1 = fmaxf(fmaxf(S1[0], S1[1]), fmaxf(S1[2], S1[3]));
    p0 = fmaxf(p0, __shfl_xor(p0, 16, 64)); p0 = fmaxf(p0, __shfl_xor(p0, 32, 64));
    p1 = fmaxf(p1, __shfl_xor(p1, 16, 64)); p1 = fmaxf(p1, __shfl_xor(p1, 32, 64));
    if (g == 0) Mx[qg][mem][l15] = float2{p0, p1};

    asm volatile("s_waitcnt lgkmcnt(0)" ::: "memory");   // B1: max exchange
    __builtin_amdgcn_s_barrier();
    __builtin_amdgcn_sched_barrier(0);

    float2 pp = Mx[qg][mem ^ 1][l15];
    float tm0 = fmaxf(p0, pp.x), tm1 = fmaxf(p1, pp.y);

    // defer-max; identical decision/history in both members (same tm values)
    if (__any(tm0 > m0 + 8.0f)) {
      float mn = fmaxf(m0, tm0), al = __expf(m0 - mn);
      l0 *= al;
      #pragma unroll
      for (int dt = 0; dt < 10; ++dt) {
        O[dt][0][0] *= al; O[dt][0][1] *= al; O[dt][0][2] *= al; O[dt][0][3] *= al;
      }
      m0 = mn;
    }
    if (__any(tm1 > m1 + 8.0f)) {
      float mn = fmaxf(m1, tm1), al = __expf(m1 - mn);
      l1 *= al;
      #pragma unroll
      for (int dt = 0; dt < 10; ++dt) {
        O[dt][1][0] *= al; O[dt][1][1] *= al; O[dt][1][2] *= al; O[dt][1][3] *= al;
      }
      m1 = mn;
    }

    // ---- exp + P write (own kv-half, both qi) + half-sums
    float ts0 = 0.f, ts1 = 0.f;
    f16x4 h0, h1;
    #pragma unroll
    for (int r = 0; r < 4; ++r) {
      float e0 = __expf(S0[r] - m0);       // bounded by e^8
      float e1 = __expf(S1[r] - m1);
      h0[r] = (f16)e0; h1[r] = (f16)e1;
      ts0 += e0; ts1 += e1;
    }
    *(f16x4*)&Psh[qg][l15][mem * 16 + g * 4]      = h0;   // qi=0 rows
    *(f16x4*)&Psh[qg][16 + l15][mem * 16 + g * 4] = h1;   // qi=1 rows
    ts0 += __shfl_xor(ts0, 16, 64); ts0 += __shfl_xor(ts0, 32, 64);
    ts1 += __shfl_xor(ts1, 16, 64); ts1 += __shfl_xor(ts1, 32, 64);
    l0 += ts0; l1 += ts1;

    asm volatile("s_waitcnt lgkmcnt(0)" ::: "memory");   // B2: P ready (no vmem wait:
    __builtin_amdgcn_s_barrier();                        //  V[t] drained at B3[t-1])
    __builtin_amdgcn_sched_barrier(0);

    // ---- PV (d-split): O^T[d-slice][32 q] += V^T . P^T
    f16x8 pb0 = *(const f16x8*)&Psh[qg][l15][g * 8];
    f16x8 pb1 = *(const f16x8*)&Psh[qg][16 + l15][g * 8];
    __builtin_amdgcn_s_setprio(1);
    #pragma unroll
    for (int dt = 0; dt < 10; ++dt) {
      if (dt < ndt) {
        f16x8 vf = *(const f16x8*)&VTsh[cur][(dtoff + dt) * 16 + l15][g * 8];
        O[dt][0] = __builtin_amdgcn_mfma_f32_16x16x32_f16(vf, pb0, O[dt][0], 0, 0, 0);
        O[dt][1] = __builtin_amdgcn_mfma_f32_16x16x32_f16(vf, pb1, O[dt][1], 0, 0, 0);
      }
    }
    __builtin_amdgcn_s_setprio(0);

    // ---- B3: drain staging (issued a full phase-pair ago) + P-read WAR guard
    asm volatile("s_waitcnt lgkmcnt(0) vmcnt(0)" ::: "memory");
    __builtin_amdgcn_s_barrier();
    __builtin_amdgcn_sched_barrier(0);
  }

  // ---- epilogue: combine pair half-sums, multiply by input row, store
  if (g == 0) Mx[qg][mem][l15] = float2{l0, l1};
  asm volatile("s_waitcnt lgkmcnt(0)" ::: "memory");
  __builtin_amdgcn_s_barrier();
  __builtin_amdgcn_sched_barrier(0);
  float2 pl = Mx[qg][mem ^ 1][l15];
  float r0 = 1.0f / (l0 + pl.x);
  float r1 = 1.0f / (l1 + pl.y);

  #pragma unroll
  for (int qi = 0; qi < 2; ++qi) {
    float rinv = qi ? r1 : r0;
    int q = qbase + qi * 16 + l15;
    const f16* mrow = Qsrc + bq + (size_t)q * DPK;
    size_t orow = (size_t)b * (4096 * 300) + (size_t)(dir * 2048 + q) * 300;
    #pragma unroll
    for (int dt = 0; dt < 10; ++dt) {
      if (dt < ndt) {
        int d = (dtoff + dt) * 16 + g * 4;
        if (d < 300) {
          f16x4 mu = *(const f16x4*)(mrow + d);
          f32x4 o;
          o[0] = O[dt][qi][0] * rinv * (float)mu[0];
          o[1] = O[dt][qi][1] * rinv * (float)mu[1];
          o[2] = O[dt][qi][2] * rinv * (float)mu[2];
          o[3] = O[dt][qi][3] * rinv * (float)mu[3];
          *(f32x4*)&out[orow + d] = o;
        }
      }
    }
  }
}

extern "C" void kernel_launch(void* const* d_in, const int* in_sizes, int n_in,
                              void* d_out, int out_size, void* d_ws, size_t ws_size,
                              hipStream_t stream) {
  const float* X = (const float*)d_in[0];
  const float* Y = (const float*)d_in[1];
  float* out = (float*)d_out;

  size_t need = (size_t)(2 * XF_ELEMS + 2 * XT_ELEMS) * sizeof(f16);  // ~83 MB
  if (ws_size < need) return;

  f16* Xf = (f16*)d_ws;
  f16* Yf = Xf + XF_ELEMS;
  f16* XT = Yf + XF_ELEMS;
  f16* YT = XT + XT_ELEMS;

  prep_kernel<<<dim3(65, 11, 32), 256, 0, stream>>>(X, Y, Xf, Yf, XT, YT);
  attn_kernel<<<dim3(256), 1024, 0, stream>>>(Xf, Yf, XT, YT, out);
}

// Round 7
// 830.906 us; speedup vs baseline: 1.0015x; 1.0015x over previous
//
#include <hip/hip_runtime.h>

typedef _Float16 f16;
typedef __attribute__((ext_vector_type(8))) _Float16 f16x8;
typedef __attribute__((ext_vector_type(4))) _Float16 f16x4;
typedef __attribute__((ext_vector_type(4))) float f32x4;

#define BATCH 16
#define NSEQ  2048
#define DDIM  300
#define DPK   328   // padded row length (f16) for row-major Xf/Yf (zeros in [300,328))
#define DPV   304   // padded d-rows for transposed XT/YT (zeros in [300,304))
#define NTP   2056  // padded q-cols for transposed copies (zeros in [2048,2056))
#define XF_ELEMS (BATCH*NSEQ*DPK)
#define XT_ELEMS (BATCH*DPV*NTP)

__device__ __forceinline__ void gl_lds16(const void* g, void* l) {
  __builtin_amdgcn_global_load_lds((const __attribute__((address_space(1))) unsigned int*)g,
                                   (__attribute__((address_space(3))) unsigned int*)l, 16, 0, 0);
}

// ---------------------------------------------------------------------------
// Preprocess: X,Y f32 -> f16 row-major (padded) + f16 transposed (padded)
// ---------------------------------------------------------------------------
__global__ __launch_bounds__(256) void prep_kernel(const float* __restrict__ X,
                                                   const float* __restrict__ Y,
                                                   f16* __restrict__ Xf, f16* __restrict__ Yf,
                                                   f16* __restrict__ XT, f16* __restrict__ YT) {
  __shared__ float tile[32][33];
  int bz   = blockIdx.z;            // 0..31 = tensor*16 + b
  int tsel = bz >> 4, b = bz & 15;
  const float* src = tsel ? Y : X;
  f16* dF = tsel ? Yf : Xf;
  f16* dT = tsel ? YT : XT;
  int d0 = blockIdx.y * 32;
  int q0 = blockIdx.x * 32;
  int tid = threadIdx.x;
  int c = tid & 31, rr = tid >> 5;

  #pragma unroll
  for (int i = 0; i < 4; ++i) {
    int qr = rr + i * 8;
    int q = q0 + qr, d = d0 + c;
    float v = 0.f;
    if (q < NSEQ && d < DDIM) v = src[(size_t)b * NSEQ * DDIM + (size_t)q * DDIM + d];
    tile[c][qr] = v;
    if (q < NSEQ && d < DPK) dF[(size_t)b * NSEQ * DPK + (size_t)q * DPK + d] = (f16)v;
  }
  __syncthreads();
  #pragma unroll
  for (int i = 0; i < 4; ++i) {
    int dr = rr + i * 8;
    int d = d0 + dr, q = q0 + c;
    if (d < DPV && q < NTP) dT[(size_t)b * DPV * NTP + (size_t)d * NTP + q] = (f16)tile[dr][c];
  }
}

// ---------------------------------------------------------------------------
// Flash attention v7 = v6 with the VGPR cap fixed.
// ONE 1024-thread block per CU: 16 waves = 8 q-groups x 2 members, QBLK=256,
// KV tile 32. Member: QK^T for qg's 32 q over its 16-kv half; PV d-split.
// K,V double-buffered; stage(t+1) right after QK^T.
// __launch_bounds__(1024, 4): 16 waves = 4/SIMD -> VGPR cap 512 (i.e. none);
// R6's bare (1024) let the compiler cap VGPR=64 -> 100% spill-bound (WRITE
// 167 MB, FETCH 2.6 GB). LDS 113 KB -> 16 waves/CU. Grid 256 = 1 block/CU.
// ---------------------------------------------------------------------------
__global__ __launch_bounds__(1024, 4) void attn_kernel(const f16* __restrict__ Xf,
                                                       const f16* __restrict__ Yf,
                                                       const f16* __restrict__ XT,
                                                       const f16* __restrict__ YT,
                                                       float* __restrict__ out) {
  __shared__ __align__(16) f16 Ksh[2][32][DPK];   // 41984 B (656 B rows)
  __shared__ __align__(16) f16 VTsh[2][DPV][40];  // 48640 B (80 B rows)
  __shared__ __align__(16) f16 Psh[8][32][40];    // 20480 B per-qg P
  __shared__ float2 Mx[8][2][16];                 //  2048 B max/lsum exchange
                                                  // total 113152 B

  int idx = blockIdx.x;
  int swz = (idx & 7) * 32 + (idx >> 3);          // 256 % 8 == 0: bijective XCD chunking
  int qt  = swz & 7;
  int b   = (swz >> 3) & 15;
  int dir = swz >> 7;

  const f16* Qsrc = dir ? Yf : Xf;
  const f16* Ksrc = dir ? Xf : Yf;
  const f16* Vts  = dir ? XT : YT;   // V^T source [DPV][NTP]

  const size_t bq = (size_t)b * NSEQ * DPK;
  const size_t bt = (size_t)b * DPV * NTP;

  int tid = threadIdx.x;
  int lane = tid & 63, wid = tid >> 6;
  int qg = wid >> 1, mem = wid & 1;
  int l15 = lane & 15, g = lane >> 4;
  int qbase = qt * 256 + qg * 32;     // q-group's 32 rows (shared by both members)

  // Q fragments (both members hold qg's 32 q): lane = Q[q=qi*16+l15][ks*32+g*8+j]
  f16x8 qf[2][10];
  #pragma unroll
  for (int qi = 0; qi < 2; ++qi) {
    const f16* qrow = Qsrc + bq + (size_t)(qbase + qi * 16 + l15) * DPK + g * 8;
    #pragma unroll
    for (int ks = 0; ks < 10; ++ks) qf[qi][ks] = *(const f16x8*)(qrow + ks * 32);
  }

  const int dtoff = mem ? 10 : 0;     // PV d-tiles: member0 d 0..159, member1 160..303
  const int ndt   = mem ? 9 : 10;

  f32x4 O[10][2];
  #pragma unroll
  for (int dt = 0; dt < 10; ++dt) {
    O[dt][0] = (f32x4){0.f, 0.f, 0.f, 0.f};
    O[dt][1] = (f32x4){0.f, 0.f, 0.f, 0.f};
  }
  float m0 = -3.0e38f, m1 = -3.0e38f, l0 = 0.f, l1 = 0.f;

  const char* gK0 = (const char*)(Ksrc + bq);
  const char* gV0 = (const char*)(Vts + bt);

  auto stageK = [&](int tt, int buf) {
    const char* gK = gK0 + (size_t)tt * (32 * DPK * 2);
    char* lK = (char*)&Ksh[buf][0][0];
    #pragma unroll
    for (int i = 0; i < 2; ++i) {          // 1312 chunks of 16 B
      int c = i * 1024 + tid;
      if (c < 1312) gl_lds16(gK + c * 16, lK + c * 16);
    }
  };
  auto stageV = [&](int tt, int buf) {
    const char* gV = gV0 + (size_t)tt * 64;
    char* lV = (char*)&VTsh[buf][0][0];
    #pragma unroll
    for (int i = 0; i < 2; ++i) {          // 304 rows x 5 slots (64 B data + 16 B pad read)
      int c = i * 1024 + tid;
      if (c < 1520) {
        int row = c / 5, slot = c - row * 5;
        gl_lds16(gV + (size_t)row * (NTP * 2) + slot * 16, lV + c * 16);
      }
    }
  };

  stageK(0, 0);
  stageV(0, 0);
  asm volatile("s_waitcnt vmcnt(0)" ::: "memory");
  __builtin_amdgcn_s_barrier();
  __builtin_amdgcn_sched_barrier(0);

  #pragma unroll 1
  for (int t = 0; t < 64; ++t) {
    int cur = t & 1;

    // ---- QK^T: S^T[own 16-kv half][qg's 32 q]
    f32x4 S0 = (f32x4){0.f,0.f,0.f,0.f}, S1 = (f32x4){0.f,0.f,0.f,0.f};
    __builtin_amdgcn_s_setprio(1);
    #pragma unroll
    for (int ks = 0; ks < 10; ++ks) {
      f16x8 a = *(const f16x8*)&Ksh[cur][mem * 16 + l15][ks * 32 + g * 8];
      S0 = __builtin_amdgcn_mfma_f32_16x16x32_f16(a, qf[0][ks], S0, 0, 0, 0);
      S1 = __builtin_amdgcn_mfma_f32_16x16x32_f16(a, qf[1][ks], S1, 0, 0, 0);
    }
    __builtin_amdgcn_s_setprio(0);

    // ---- stage t+1 early (WAR-safe: buf^1 reads finished before B3 of t-1);
    //      loads get the whole softmax+PV window to land before B3's vmcnt(0).
    if (t < 63) { stageK(t + 1, cur ^ 1); stageV(t + 1, cur ^ 1); }

    // ---- partial max over own 16 kv (per q-col = l15, per qi)
    float p0 = fmaxf(fmaxf(S0[0], S0[1]), fmaxf(S0[2], S0[3]));
    float p1 = fmaxf(fmaxf(S1[0], S1[1]), fmaxf(S1[2], S1[3]));
    p0 = fmaxf(p0, __shfl_xor(p0, 16, 64)); p0 = fmaxf(p0, __shfl_xor(p0, 32, 64));
    p1 = fmaxf(p1, __shfl_xor(p1, 16, 64)); p1 = fmaxf(p1, __shfl_xor(p1, 32, 64));
    if (g == 0) Mx[qg][mem][l15] = float2{p0, p1};

    asm volatile("s_waitcnt lgkmcnt(0)" ::: "memory");   // B1: max exchange
    __builtin_amdgcn_s_barrier();
    __builtin_amdgcn_sched_barrier(0);

    float2 pp = Mx[qg][mem ^ 1][l15];
    float tm0 = fmaxf(p0, pp.x), tm1 = fmaxf(p1, pp.y);

    // defer-max; identical decision/history in both members (same tm values)
    if (__any(tm0 > m0 + 8.0f)) {
      float mn = fmaxf(m0, tm0), al = __expf(m0 - mn);
      l0 *= al;
      #pragma unroll
      for (int dt = 0; dt < 10; ++dt) {
        O[dt][0][0] *= al; O[dt][0][1] *= al; O[dt][0][2] *= al; O[dt][0][3] *= al;
      }
      m0 = mn;
    }
    if (__any(tm1 > m1 + 8.0f)) {
      float mn = fmaxf(m1, tm1), al = __expf(m1 - mn);
      l1 *= al;
      #pragma unroll
      for (int dt = 0; dt < 10; ++dt) {
        O[dt][1][0] *= al; O[dt][1][1] *= al; O[dt][1][2] *= al; O[dt][1][3] *= al;
      }
      m1 = mn;
    }

    // ---- exp + P write (own kv-half, both qi) + half-sums
    float ts0 = 0.f, ts1 = 0.f;
    f16x4 h0, h1;
    #pragma unroll
    for (int r = 0; r < 4; ++r) {
      float e0 = __expf(S0[r] - m0);       // bounded by e^8
      float e1 = __expf(S1[r] - m1);
      h0[r] = (f16)e0; h1[r] = (f16)e1;
      ts0 += e0; ts1 += e1;
    }
    *(f16x4*)&Psh[qg][l15][mem * 16 + g * 4]      = h0;   // qi=0 rows
    *(f16x4*)&Psh[qg][16 + l15][mem * 16 + g * 4] = h1;   // qi=1 rows
    ts0 += __shfl_xor(ts0, 16, 64); ts0 += __shfl_xor(ts0, 32, 64);
    ts1 += __shfl_xor(ts1, 16, 64); ts1 += __shfl_xor(ts1, 32, 64);
    l0 += ts0; l1 += ts1;

    asm volatile("s_waitcnt lgkmcnt(0)" ::: "memory");   // B2: P ready (no vmem wait:
    __builtin_amdgcn_s_barrier();                        //  V[t] drained at B3[t-1])
    __builtin_amdgcn_sched_barrier(0);

    // ---- PV (d-split): O^T[d-slice][32 q] += V^T . P^T
    f16x8 pb0 = *(const f16x8*)&Psh[qg][l15][g * 8];
    f16x8 pb1 = *(const f16x8*)&Psh[qg][16 + l15][g * 8];
    __builtin_amdgcn_s_setprio(1);
    #pragma unroll
    for (int dt = 0; dt < 10; ++dt) {
      if (dt < ndt) {
        f16x8 vf = *(const f16x8*)&VTsh[cur][(dtoff + dt) * 16 + l15][g * 8];
        O[dt][0] = __builtin_amdgcn_mfma_f32_16x16x32_f16(vf, pb0, O[dt][0], 0, 0, 0);
        O[dt][1] = __builtin_amdgcn_mfma_f32_16x16x32_f16(vf, pb1, O[dt][1], 0, 0, 0);
      }
    }
    __builtin_amdgcn_s_setprio(0);

    // ---- B3: drain staging (issued a full phase-pair ago) + P-read WAR guard
    asm volatile("s_waitcnt lgkmcnt(0) vmcnt(0)" ::: "memory");
    __builtin_amdgcn_s_barrier();
    __builtin_amdgcn_sched_barrier(0);
  }

  // ---- epilogue: combine pair half-sums, multiply by input row, store
  if (g == 0) Mx[qg][mem][l15] = float2{l0, l1};
  asm volatile("s_waitcnt lgkmcnt(0)" ::: "memory");
  __builtin_amdgcn_s_barrier();
  __builtin_amdgcn_sched_barrier(0);
  float2 pl = Mx[qg][mem ^ 1][l15];
  float r0 = 1.0f / (l0 + pl.x);
  float r1 = 1.0f / (l1 + pl.y);

  #pragma unroll
  for (int qi = 0; qi < 2; ++qi) {
    float rinv = qi ? r1 : r0;
    int q = qbase + qi * 16 + l15;
    const f16* mrow = Qsrc + bq + (size_t)q * DPK;
    size_t orow = (size_t)b * (4096 * 300) + (size_t)(dir * 2048 + q) * 300;
    #pragma unroll
    for (int dt = 0; dt < 10; ++dt) {
      if (dt < ndt) {
        int d = (dtoff + dt) * 16 + g * 4;
        if (d < 300) {
          f16x4 mu = *(const f16x4*)(mrow + d);
          f32x4 o;
          o[0] = O[dt][qi][0] * rinv * (float)mu[0];
          o[1] = O[dt][qi][1] * rinv * (float)mu[1];
          o[2] = O[dt][qi][2] * rinv * (float)mu[2];
          o[3] = O[dt][qi][3] * rinv * (float)mu[3];
          *(f32x4*)&out[orow + d] = o;
        }
      }
    }
  }
}

extern "C" void kernel_launch(void* const* d_in, const int* in_sizes, int n_in,
                              void* d_out, int out_size, void* d_ws, size_t ws_size,
                              hipStream_t stream) {
  const float* X = (const float*)d_in[0];
  const float* Y = (const float*)d_in[1];
  float* out = (float*)d_out;

  size_t need = (size_t)(2 * XF_ELEMS + 2 * XT_ELEMS) * sizeof(f16);  // ~83 MB
  if (ws_size < need) return;

  f16* Xf = (f16*)d_ws;
  f16* Yf = Xf + XF_ELEMS;
  f16* XT = Yf + XF_ELEMS;
  f16* YT = XT + XT_ELEMS;

  prep_kernel<<<dim3(65, 11, 32), 256, 0, stream>>>(X, Y, Xf, Yf, XT, YT);
  attn_kernel<<<dim3(256), 1024, 0, stream>>>(Xf, Yf, XT, YT, out);
}

// Round 8
// 830.819 us; speedup vs baseline: 1.0016x; 1.0001x over previous
//
#include <hip/hip_runtime.h>

typedef _Float16 f16;
typedef __attribute__((ext_vector_type(8))) _Float16 f16x8;
typedef __attribute__((ext_vector_type(4))) _Float16 f16x4;
typedef __attribute__((ext_vector_type(4))) float f32x4;

#define BATCH 16
#define NSEQ  2048
#define DDIM  300
#define DPK   328   // padded row length (f16) for row-major Xf/Yf (zeros in [300,328))
#define DPV   304   // padded d-rows for transposed XT/YT (zeros in [300,304))
#define NTP   2056  // padded q-cols for transposed copies (zeros in [2048,2056))
#define XF_ELEMS (BATCH*NSEQ*DPK)
#define XT_ELEMS (BATCH*DPV*NTP)

__device__ __forceinline__ void gl_lds16(const void* g, void* l) {
  __builtin_amdgcn_global_load_lds((const __attribute__((address_space(1))) unsigned int*)g,
                                   (__attribute__((address_space(3))) unsigned int*)l, 16, 0, 0);
}

// ---------------------------------------------------------------------------
// Preprocess: X,Y f32 -> f16 row-major (padded) + f16 transposed (padded)
// ---------------------------------------------------------------------------
__global__ __launch_bounds__(256) void prep_kernel(const float* __restrict__ X,
                                                   const float* __restrict__ Y,
                                                   f16* __restrict__ Xf, f16* __restrict__ Yf,
                                                   f16* __restrict__ XT, f16* __restrict__ YT) {
  __shared__ float tile[32][33];
  int bz   = blockIdx.z;            // 0..31 = tensor*16 + b
  int tsel = bz >> 4, b = bz & 15;
  const float* src = tsel ? Y : X;
  f16* dF = tsel ? Yf : Xf;
  f16* dT = tsel ? YT : XT;
  int d0 = blockIdx.y * 32;
  int q0 = blockIdx.x * 32;
  int tid = threadIdx.x;
  int c = tid & 31, rr = tid >> 5;

  #pragma unroll
  for (int i = 0; i < 4; ++i) {
    int qr = rr + i * 8;
    int q = q0 + qr, d = d0 + c;
    float v = 0.f;
    if (q < NSEQ && d < DDIM) v = src[(size_t)b * NSEQ * DDIM + (size_t)q * DDIM + d];
    tile[c][qr] = v;
    if (q < NSEQ && d < DPK) dF[(size_t)b * NSEQ * DPK + (size_t)q * DPK + d] = (f16)v;
  }
  __syncthreads();
  #pragma unroll
  for (int i = 0; i < 4; ++i) {
    int dr = rr + i * 8;
    int d = d0 + dr, q = q0 + c;
    if (d < DPV && q < NTP) dT[(size_t)b * DPV * NTP + (size_t)d * NTP + q] = (f16)tile[dr][c];
  }
}

// ---------------------------------------------------------------------------
// Flash attention v8 = v7 with the VGPR budget actually unlocked.
// R6 (bare 1024) and R7 (1024,4) both got VGPR=64: launch_bounds' 2nd arg is
// a MIN waves/EU — the allocator still TARGETED 8 waves/EU (512/8=64 regs)
// and spilled everything (FETCH 2.6 GB/dispatch). Fix: amdgpu_waves_per_eu
// with an explicit MAX of 4 -> register budget 512/4 = 128 >= the ~108 this
// per-thread state needs (R5 measured). Structure unchanged from v7:
// one 1024-thread block/CU, 16 waves = 8 qg x 2 members, QBLK=256, KV=32,
// kv-split QK^T + d-split PV, K/V double-buffered, LDS 113 KB.
// ---------------------------------------------------------------------------
__global__ __launch_bounds__(1024)
__attribute__((amdgpu_waves_per_eu(2, 4)))
void attn_kernel(const f16* __restrict__ Xf,
                 const f16* __restrict__ Yf,
                 const f16* __restrict__ XT,
                 const f16* __restrict__ YT,
                 float* __restrict__ out) {
  __shared__ __align__(16) f16 Ksh[2][32][DPK];   // 41984 B (656 B rows)
  __shared__ __align__(16) f16 VTsh[2][DPV][40];  // 48640 B (80 B rows)
  __shared__ __align__(16) f16 Psh[8][32][40];    // 20480 B per-qg P
  __shared__ float2 Mx[8][2][16];                 //  2048 B max/lsum exchange
                                                  // total 113152 B

  int idx = blockIdx.x;
  int swz = (idx & 7) * 32 + (idx >> 3);          // 256 % 8 == 0: bijective XCD chunking
  int qt  = swz & 7;
  int b   = (swz >> 3) & 15;
  int dir = swz >> 7;

  const f16* Qsrc = dir ? Yf : Xf;
  const f16* Ksrc = dir ? Xf : Yf;
  const f16* Vts  = dir ? XT : YT;   // V^T source [DPV][NTP]

  const size_t bq = (size_t)b * NSEQ * DPK;
  const size_t bt = (size_t)b * DPV * NTP;

  int tid = threadIdx.x;
  int lane = tid & 63, wid = tid >> 6;
  int qg = wid >> 1, mem = wid & 1;
  int l15 = lane & 15, g = lane >> 4;
  int qbase = qt * 256 + qg * 32;     // q-group's 32 rows (shared by both members)

  // Q fragments (both members hold qg's 32 q): lane = Q[q=qi*16+l15][ks*32+g*8+j]
  f16x8 qf[2][10];
  #pragma unroll
  for (int qi = 0; qi < 2; ++qi) {
    const f16* qrow = Qsrc + bq + (size_t)(qbase + qi * 16 + l15) * DPK + g * 8;
    #pragma unroll
    for (int ks = 0; ks < 10; ++ks) qf[qi][ks] = *(const f16x8*)(qrow + ks * 32);
  }

  const int dtoff = mem ? 10 : 0;     // PV d-tiles: member0 d 0..159, member1 160..303
  const int ndt   = mem ? 9 : 10;

  f32x4 O[10][2];
  #pragma unroll
  for (int dt = 0; dt < 10; ++dt) {
    O[dt][0] = (f32x4){0.f, 0.f, 0.f, 0.f};
    O[dt][1] = (f32x4){0.f, 0.f, 0.f, 0.f};
  }
  float m0 = -3.0e38f, m1 = -3.0e38f, l0 = 0.f, l1 = 0.f;

  const char* gK0 = (const char*)(Ksrc + bq);
  const char* gV0 = (const char*)(Vts + bt);

  auto stageK = [&](int tt, int buf) {
    const char* gK = gK0 + (size_t)tt * (32 * DPK * 2);
    char* lK = (char*)&Ksh[buf][0][0];
    #pragma unroll
    for (int i = 0; i < 2; ++i) {          // 1312 chunks of 16 B
      int c = i * 1024 + tid;
      if (c < 1312) gl_lds16(gK + c * 16, lK + c * 16);
    }
  };
  auto stageV = [&](int tt, int buf) {
    const char* gV = gV0 + (size_t)tt * 64;
    char* lV = (char*)&VTsh[buf][0][0];
    #pragma unroll
    for (int i = 0; i < 2; ++i) {          // 304 rows x 5 slots (64 B data + 16 B pad read)
      int c = i * 1024 + tid;
      if (c < 1520) {
        int row = c / 5, slot = c - row * 5;
        gl_lds16(gV + (size_t)row * (NTP * 2) + slot * 16, lV + c * 16);
      }
    }
  };

  stageK(0, 0);
  stageV(0, 0);
  asm volatile("s_waitcnt vmcnt(0)" ::: "memory");
  __builtin_amdgcn_s_barrier();
  __builtin_amdgcn_sched_barrier(0);

  #pragma unroll 1
  for (int t = 0; t < 64; ++t) {
    int cur = t & 1;

    // ---- QK^T: S^T[own 16-kv half][qg's 32 q]
    f32x4 S0 = (f32x4){0.f,0.f,0.f,0.f}, S1 = (f32x4){0.f,0.f,0.f,0.f};
    __builtin_amdgcn_s_setprio(1);
    #pragma unroll
    for (int ks = 0; ks < 10; ++ks) {
      f16x8 a = *(const f16x8*)&Ksh[cur][mem * 16 + l15][ks * 32 + g * 8];
      S0 = __builtin_amdgcn_mfma_f32_16x16x32_f16(a, qf[0][ks], S0, 0, 0, 0);
      S1 = __builtin_amdgcn_mfma_f32_16x16x32_f16(a, qf[1][ks], S1, 0, 0, 0);
    }
    __builtin_amdgcn_s_setprio(0);

    // ---- stage t+1 early (WAR-safe: buf^1 reads finished before B3 of t-1);
    //      loads get the whole softmax+PV window to land before B3's vmcnt(0).
    if (t < 63) { stageK(t + 1, cur ^ 1); stageV(t + 1, cur ^ 1); }

    // ---- partial max over own 16 kv (per q-col = l15, per qi)
    float p0 = fmaxf(fmaxf(S0[0], S0[1]), fmaxf(S0[2], S0[3]));
    float p1 = fmaxf(fmaxf(S1[0], S1[1]), fmaxf(S1[2], S1[3]));
    p0 = fmaxf(p0, __shfl_xor(p0, 16, 64)); p0 = fmaxf(p0, __shfl_xor(p0, 32, 64));
    p1 = fmaxf(p1, __shfl_xor(p1, 16, 64)); p1 = fmaxf(p1, __shfl_xor(p1, 32, 64));
    if (g == 0) Mx[qg][mem][l15] = float2{p0, p1};

    asm volatile("s_waitcnt lgkmcnt(0)" ::: "memory");   // B1: max exchange
    __builtin_amdgcn_s_barrier();
    __builtin_amdgcn_sched_barrier(0);

    float2 pp = Mx[qg][mem ^ 1][l15];
    float tm0 = fmaxf(p0, pp.x), tm1 = fmaxf(p1, pp.y);

    // defer-max; identical decision/history in both members (same tm values)
    if (__any(tm0 > m0 + 8.0f)) {
      float mn = fmaxf(m0, tm0), al = __expf(m0 - mn);
      l0 *= al;
      #pragma unroll
      for (int dt = 0; dt < 10; ++dt) {
        O[dt][0][0] *= al; O[dt][0][1] *= al; O[dt][0][2] *= al; O[dt][0][3] *= al;
      }
      m0 = mn;
    }
    if (__any(tm1 > m1 + 8.0f)) {
      float mn = fmaxf(m1, tm1), al = __expf(m1 - mn);
      l1 *= al;
      #pragma unroll
      for (int dt = 0; dt < 10; ++dt) {
        O[dt][1][0] *= al; O[dt][1][1] *= al; O[dt][1][2] *= al; O[dt][1][3] *= al;
      }
      m1 = mn;
    }

    // ---- exp + P write (own kv-half, both qi) + half-sums
    float ts0 = 0.f, ts1 = 0.f;
    f16x4 h0, h1;
    #pragma unroll
    for (int r = 0; r < 4; ++r) {
      float e0 = __expf(S0[r] - m0);       // bounded by e^8
      float e1 = __expf(S1[r] - m1);
      h0[r] = (f16)e0; h1[r] = (f16)e1;
      ts0 += e0; ts1 += e1;
    }
    *(f16x4*)&Psh[qg][l15][mem * 16 + g * 4]      = h0;   // qi=0 rows
    *(f16x4*)&Psh[qg][16 + l15][mem * 16 + g * 4] = h1;   // qi=1 rows
    ts0 += __shfl_xor(ts0, 16, 64); ts0 += __shfl_xor(ts0, 32, 64);
    ts1 += __shfl_xor(ts1, 16, 64); ts1 += __shfl_xor(ts1, 32, 64);
    l0 += ts0; l1 += ts1;

    asm volatile("s_waitcnt lgkmcnt(0)" ::: "memory");   // B2: P ready (no vmem wait:
    __builtin_amdgcn_s_barrier();                        //  V[t] drained at B3[t-1])
    __builtin_amdgcn_sched_barrier(0);

    // ---- PV (d-split): O^T[d-slice][32 q] += V^T . P^T
    f16x8 pb0 = *(const f16x8*)&Psh[qg][l15][g * 8];
    f16x8 pb1 = *(const f16x8*)&Psh[qg][16 + l15][g * 8];
    __builtin_amdgcn_s_setprio(1);
    #pragma unroll
    for (int dt = 0; dt < 10; ++dt) {
      if (dt < ndt) {
        f16x8 vf = *(const f16x8*)&VTsh[cur][(dtoff + dt) * 16 + l15][g * 8];
        O[dt][0] = __builtin_amdgcn_mfma_f32_16x16x32_f16(vf, pb0, O[dt][0], 0, 0, 0);
        O[dt][1] = __builtin_amdgcn_mfma_f32_16x16x32_f16(vf, pb1, O[dt][1], 0, 0, 0);
      }
    }
    __builtin_amdgcn_s_setprio(0);

    // ---- B3: drain staging (issued a full phase-pair ago) + P-read WAR guard
    asm volatile("s_waitcnt lgkmcnt(0) vmcnt(0)" ::: "memory");
    __builtin_amdgcn_s_barrier();
    __builtin_amdgcn_sched_barrier(0);
  }

  // ---- epilogue: combine pair half-sums, multiply by input row, store
  if (g == 0) Mx[qg][mem][l15] = float2{l0, l1};
  asm volatile("s_waitcnt lgkmcnt(0)" ::: "memory");
  __builtin_amdgcn_s_barrier();
  __builtin_amdgcn_sched_barrier(0);
  float2 pl = Mx[qg][mem ^ 1][l15];
  float r0 = 1.0f / (l0 + pl.x);
  float r1 = 1.0f / (l1 + pl.y);

  #pragma unroll
  for (int qi = 0; qi < 2; ++qi) {
    float rinv = qi ? r1 : r0;
    int q = qbase + qi * 16 + l15;
    const f16* mrow = Qsrc + bq + (size_t)q * DPK;
    size_t orow = (size_t)b * (4096 * 300) + (size_t)(dir * 2048 + q) * 300;
    #pragma unroll
    for (int dt = 0; dt < 10; ++dt) {
      if (dt < ndt) {
        int d = (dtoff + dt) * 16 + g * 4;
        if (d < 300) {
          f16x4 mu = *(const f16x4*)(mrow + d);
          f32x4 o;
          o[0] = O[dt][qi][0] * rinv * (float)mu[0];
          o[1] = O[dt][qi][1] * rinv * (float)mu[1];
          o[2] = O[dt][qi][2] * rinv * (float)mu[2];
          o[3] = O[dt][qi][3] * rinv * (float)mu[3];
          *(f32x4*)&out[orow + d] = o;
        }
      }
    }
  }
}

extern "C" void kernel_launch(void* const* d_in, const int* in_sizes, int n_in,
                              void* d_out, int out_size, void* d_ws, size_t ws_size,
                              hipStream_t stream) {
  const float* X = (const float*)d_in[0];
  const float* Y = (const float*)d_in[1];
  float* out = (float*)d_out;

  size_t need = (size_t)(2 * XF_ELEMS + 2 * XT_ELEMS) * sizeof(f16);  // ~83 MB
  if (ws_size < need) return;

  f16* Xf = (f16*)d_ws;
  f16* Yf = Xf + XF_ELEMS;
  f16* XT = Yf + XF_ELEMS;
  f16* YT = XT + XT_ELEMS;

  prep_kernel<<<dim3(65, 11, 32), 256, 0, stream>>>(X, Y, Xf, Yf, XT, YT);
  attn_kernel<<<dim3(256), 1024, 0, stream>>>(Xf, Yf, XT, YT, out);
}

// Round 9
// 282.332 us; speedup vs baseline: 2.9474x; 2.9427x over previous
//
#include <hip/hip_runtime.h>

typedef _Float16 f16;
typedef __attribute__((ext_vector_type(8))) _Float16 f16x8;
typedef __attribute__((ext_vector_type(4))) _Float16 f16x4;
typedef __attribute__((ext_vector_type(4))) float f32x4;

#define BATCH 16
#define NSEQ  2048
#define DDIM  300
#define DPK   328   // padded row length (f16) for row-major Xf/Yf (zeros in [300,328))
#define DPV   304   // padded d-rows for transposed XT/YT (zeros in [300,304))
#define NTP   2056  // padded q-cols for transposed copies (zeros in [2048,2056))
#define XF_ELEMS (BATCH*NSEQ*DPK)
#define XT_ELEMS (BATCH*DPV*NTP)

__device__ __forceinline__ void gl_lds16(const void* g, void* l) {
  __builtin_amdgcn_global_load_lds((const __attribute__((address_space(1))) unsigned int*)g,
                                   (__attribute__((address_space(3))) unsigned int*)l, 16, 0, 0);
}

// ---------------------------------------------------------------------------
// Preprocess: X,Y f32 -> f16 row-major (padded) + f16 transposed (padded)
// ---------------------------------------------------------------------------
__global__ __launch_bounds__(256) void prep_kernel(const float* __restrict__ X,
                                                   const float* __restrict__ Y,
                                                   f16* __restrict__ Xf, f16* __restrict__ Yf,
                                                   f16* __restrict__ XT, f16* __restrict__ YT) {
  __shared__ float tile[32][33];
  int bz   = blockIdx.z;            // 0..31 = tensor*16 + b
  int tsel = bz >> 4, b = bz & 15;
  const float* src = tsel ? Y : X;
  f16* dF = tsel ? Yf : Xf;
  f16* dT = tsel ? YT : XT;
  int d0 = blockIdx.y * 32;
  int q0 = blockIdx.x * 32;
  int tid = threadIdx.x;
  int c = tid & 31, rr = tid >> 5;

  #pragma unroll
  for (int i = 0; i < 4; ++i) {
    int qr = rr + i * 8;
    int q = q0 + qr, d = d0 + c;
    float v = 0.f;
    if (q < NSEQ && d < DDIM) v = src[(size_t)b * NSEQ * DDIM + (size_t)q * DDIM + d];
    tile[c][qr] = v;
    if (q < NSEQ && d < DPK) dF[(size_t)b * NSEQ * DPK + (size_t)q * DPK + d] = (f16)v;
  }
  __syncthreads();
  #pragma unroll
  for (int i = 0; i < 4; ++i) {
    int dr = rr + i * 8;
    int d = d0 + dr, q = q0 + c;
    if (d < DPV && q < NTP) dT[(size_t)b * DPV * NTP + (size_t)d * NTP + q] = (f16)tile[dr][c];
  }
}

// ---------------------------------------------------------------------------
// Flash attention v9: R5 base (512 thr, 8 waves = 4 qg x 2 members, QBLK=128,
// KV tile 32, kv-split QK^T + d-split PV, K/V dbuf, LDS 101 KB, 1 block/CU)
// with a SOFTWARE-PIPELINED 2-barrier schedule: iter t runs one merged MFMA
// cluster {QK^T[t] + PV[t-1]}, then stages K[t+1],V[t], then B1 (max exch),
// then exp/P-write[t]/O-rescale, then B2 (lgkm + the ONLY vmcnt(0), draining
// loads issued ~1500 cyc earlier). PV trails one tile; epilogue does PV[63].
// 1024-thread variants are dead: gfx950 pins VGPR=64 for 1024-thr blocks
// (R6/R7/R8 all spill-bound). __launch_bounds__(512,1): R5-proven VGPR=108.
// ---------------------------------------------------------------------------
__global__ __launch_bounds__(512, 1) void attn_kernel(const f16* __restrict__ Xf,
                                                      const f16* __restrict__ Yf,
                                                      const f16* __restrict__ XT,
                                                      const f16* __restrict__ YT,
                                                      float* __restrict__ out) {
  __shared__ __align__(16) f16 Ksh[2][32][DPK];   // 41984 B (656 B rows)
  __shared__ __align__(16) f16 VTsh[2][DPV][40];  // 48640 B (80 B rows)
  __shared__ __align__(16) f16 Psh[4][32][40];    // 10240 B per-qg P
  __shared__ float2 Mx[4][2][16];                 //   512 B max/lsum exchange
                                                  // total 101376 B

  int idx = blockIdx.x;
  int swz = (idx & 7) * 64 + (idx >> 3);          // 512 % 8 == 0: bijective XCD chunking
  int qt  = swz & 15;
  int b   = (swz >> 4) & 15;
  int dir = swz >> 8;

  const f16* Qsrc = dir ? Yf : Xf;
  const f16* Ksrc = dir ? Xf : Yf;
  const f16* Vts  = dir ? XT : YT;   // V^T source [DPV][NTP]

  const size_t bq = (size_t)b * NSEQ * DPK;
  const size_t bt = (size_t)b * DPV * NTP;

  int tid = threadIdx.x;
  int lane = tid & 63, wid = tid >> 6;
  int qg = wid >> 1, mem = wid & 1;
  int l15 = lane & 15, g = lane >> 4;
  int qbase = qt * 128 + qg * 32;     // q-group's 32 rows (shared by both members)

  // Q fragments (both members hold qg's 32 q): lane = Q[q=qi*16+l15][ks*32+g*8+j]
  f16x8 qf[2][10];
  #pragma unroll
  for (int qi = 0; qi < 2; ++qi) {
    const f16* qrow = Qsrc + bq + (size_t)(qbase + qi * 16 + l15) * DPK + g * 8;
    #pragma unroll
    for (int ks = 0; ks < 10; ++ks) qf[qi][ks] = *(const f16x8*)(qrow + ks * 32);
  }

  const int dtoff = mem ? 10 : 0;     // PV d-tiles: member0 d 0..159, member1 160..303
  const int ndt   = mem ? 9 : 10;

  f32x4 O[10][2];
  #pragma unroll
  for (int dt = 0; dt < 10; ++dt) {
    O[dt][0] = (f32x4){0.f, 0.f, 0.f, 0.f};
    O[dt][1] = (f32x4){0.f, 0.f, 0.f, 0.f};
  }
  float m0 = -3.0e38f, m1 = -3.0e38f, l0 = 0.f, l1 = 0.f;

  const char* gK0 = (const char*)(Ksrc + bq);
  const char* gV0 = (const char*)(Vts + bt);

  auto stageK = [&](int tt, int buf) {
    const char* gK = gK0 + (size_t)tt * (32 * DPK * 2);
    char* lK = (char*)&Ksh[buf][0][0];
    #pragma unroll
    for (int i = 0; i < 3; ++i) {          // 1312 chunks of 16 B
      int c = i * 512 + tid;
      if (c < 1312) gl_lds16(gK + c * 16, lK + c * 16);
    }
  };
  auto stageV = [&](int tt, int buf) {
    const char* gV = gV0 + (size_t)tt * 64;
    char* lV = (char*)&VTsh[buf][0][0];
    #pragma unroll
    for (int i = 0; i < 3; ++i) {          // 304 rows x 5 slots (64 B data + 16 B pad read)
      int c = i * 512 + tid;
      if (c < 1520) {
        int row = c / 5, slot = c - row * 5;
        gl_lds16(gV + (size_t)row * (NTP * 2) + slot * 16, lV + c * 16);
      }
    }
  };

  stageK(0, 0);                             // K[0] -> buf0
  asm volatile("s_waitcnt vmcnt(0)" ::: "memory");
  __builtin_amdgcn_s_barrier();
  __builtin_amdgcn_sched_barrier(0);

  #pragma unroll 1
  for (int t = 0; t < 64; ++t) {
    int kcur = t & 1;                       // K[t] buffer
    int vprev = (t - 1) & 1;                // V[t-1] buffer (valid for t>0)

    // ---- Phase 1: merged MFMA cluster — QK^T[t] + PV[t-1]
    f32x4 S0 = (f32x4){0.f,0.f,0.f,0.f}, S1 = (f32x4){0.f,0.f,0.f,0.f};
    __builtin_amdgcn_s_setprio(1);
    if (t > 0) {
      f16x8 pb0 = *(const f16x8*)&Psh[qg][l15][g * 8];
      f16x8 pb1 = *(const f16x8*)&Psh[qg][16 + l15][g * 8];
      #pragma unroll
      for (int dt = 0; dt < 10; ++dt) {
        if (dt < ndt) {
          f16x8 vf = *(const f16x8*)&VTsh[vprev][(dtoff + dt) * 16 + l15][g * 8];
          O[dt][0] = __builtin_amdgcn_mfma_f32_16x16x32_f16(vf, pb0, O[dt][0], 0, 0, 0);
          O[dt][1] = __builtin_amdgcn_mfma_f32_16x16x32_f16(vf, pb1, O[dt][1], 0, 0, 0);
        }
      }
    }
    #pragma unroll
    for (int ks = 0; ks < 10; ++ks) {
      f16x8 a = *(const f16x8*)&Ksh[kcur][mem * 16 + l15][ks * 32 + g * 8];
      S0 = __builtin_amdgcn_mfma_f32_16x16x32_f16(a, qf[0][ks], S0, 0, 0, 0);
      S1 = __builtin_amdgcn_mfma_f32_16x16x32_f16(a, qf[1][ks], S1, 0, 0, 0);
    }
    __builtin_amdgcn_s_setprio(0);

    // ---- Phase 2: stage K[t+1] -> buf (t+1)&1, V[t] -> buf t&1.
    //      WAR-safe: those buffers' last readers finished before B2[t-1].
    if (t < 63) stageK(t + 1, kcur ^ 1);
    stageV(t, kcur);

    // ---- Phase 3: partial max over own 16 kv (per q-col = l15, per qi)
    float p0 = fmaxf(fmaxf(S0[0], S0[1]), fmaxf(S0[2], S0[3]));
    float p1 = fmaxf(fmaxf(S1[0], S1[1]), fmaxf(S1[2], S1[3]));
    p0 = fmaxf(p0, __shfl_xor(p0, 16, 64)); p0 = fmaxf(p0, __shfl_xor(p0, 32, 64));
    p1 = fmaxf(p1, __shfl_xor(p1, 16, 64)); p1 = fmaxf(p1, __shfl_xor(p1, 32, 64));
    if (g == 0) Mx[qg][mem][l15] = float2{p0, p1};

    asm volatile("s_waitcnt lgkmcnt(0)" ::: "memory");   // B1: max exchange visible;
    __builtin_amdgcn_s_barrier();                        //  also fences P[t-1] reads
    __builtin_amdgcn_sched_barrier(0);                   //  from P[t] writes below

    // ---- Phase 4: combine maxes, defer-max rescale, exp, P-write, sums
    float2 pp = Mx[qg][mem ^ 1][l15];
    float tm0 = fmaxf(p0, pp.x), tm1 = fmaxf(p1, pp.y);

    if (__any(tm0 > m0 + 8.0f)) {          // defer-max (identical in both members)
      float mn = fmaxf(m0, tm0), al = __expf(m0 - mn);
      l0 *= al;
      #pragma unroll
      for (int dt = 0; dt < 10; ++dt) {
        O[dt][0][0] *= al; O[dt][0][1] *= al; O[dt][0][2] *= al; O[dt][0][3] *= al;
      }
      m0 = mn;
    }
    if (__any(tm1 > m1 + 8.0f)) {
      float mn = fmaxf(m1, tm1), al = __expf(m1 - mn);
      l1 *= al;
      #pragma unroll
      for (int dt = 0; dt < 10; ++dt) {
        O[dt][1][0] *= al; O[dt][1][1] *= al; O[dt][1][2] *= al; O[dt][1][3] *= al;
      }
      m1 = mn;
    }

    float ts0 = 0.f, ts1 = 0.f;
    f16x4 h0, h1;
    #pragma unroll
    for (int r = 0; r < 4; ++r) {
      float e0 = __expf(S0[r] - m0);       // bounded by e^8
      float e1 = __expf(S1[r] - m1);
      h0[r] = (f16)e0; h1[r] = (f16)e1;
      ts0 += e0; ts1 += e1;
    }
    *(f16x4*)&Psh[qg][l15][mem * 16 + g * 4]      = h0;   // qi=0 rows
    *(f16x4*)&Psh[qg][16 + l15][mem * 16 + g * 4] = h1;   // qi=1 rows
    ts0 += __shfl_xor(ts0, 16, 64); ts0 += __shfl_xor(ts0, 32, 64);
    ts1 += __shfl_xor(ts1, 16, 64); ts1 += __shfl_xor(ts1, 32, 64);
    l0 += ts0; l1 += ts1;

    // ---- B2: P[t] visible + drain K[t+1],V[t] (issued ~1500 cyc earlier)
    asm volatile("s_waitcnt lgkmcnt(0) vmcnt(0)" ::: "memory");
    __builtin_amdgcn_s_barrier();
    __builtin_amdgcn_sched_barrier(0);
  }

  // ---- Epilogue PV[63] (trailing tile of the pipeline)
  {
    int vprev = 63 & 1;
    f16x8 pb0 = *(const f16x8*)&Psh[qg][l15][g * 8];
    f16x8 pb1 = *(const f16x8*)&Psh[qg][16 + l15][g * 8];
    __builtin_amdgcn_s_setprio(1);
    #pragma unroll
    for (int dt = 0; dt < 10; ++dt) {
      if (dt < ndt) {
        f16x8 vf = *(const f16x8*)&VTsh[vprev][(dtoff + dt) * 16 + l15][g * 8];
        O[dt][0] = __builtin_amdgcn_mfma_f32_16x16x32_f16(vf, pb0, O[dt][0], 0, 0, 0);
        O[dt][1] = __builtin_amdgcn_mfma_f32_16x16x32_f16(vf, pb1, O[dt][1], 0, 0, 0);
      }
    }
    __builtin_amdgcn_s_setprio(0);
  }

  // ---- combine pair half-sums, multiply by input row, store
  if (g == 0) Mx[qg][mem][l15] = float2{l0, l1};
  asm volatile("s_waitcnt lgkmcnt(0)" ::: "memory");
  __builtin_amdgcn_s_barrier();
  __builtin_amdgcn_sched_barrier(0);
  float2 pl = Mx[qg][mem ^ 1][l15];
  float r0 = 1.0f / (l0 + pl.x);
  float r1 = 1.0f / (l1 + pl.y);

  #pragma unroll
  for (int qi = 0; qi < 2; ++qi) {
    float rinv = qi ? r1 : r0;
    int q = qbase + qi * 16 + l15;
    const f16* mrow = Qsrc + bq + (size_t)q * DPK;
    size_t orow = (size_t)b * (4096 * 300) + (size_t)(dir * 2048 + q) * 300;
    #pragma unroll
    for (int dt = 0; dt < 10; ++dt) {
      if (dt < ndt) {
        int d = (dtoff + dt) * 16 + g * 4;
        if (d < 300) {
          f16x4 mu = *(const f16x4*)(mrow + d);
          f32x4 o;
          o[0] = O[dt][qi][0] * rinv * (float)mu[0];
          o[1] = O[dt][qi][1] * rinv * (float)mu[1];
          o[2] = O[dt][qi][2] * rinv * (float)mu[2];
          o[3] = O[dt][qi][3] * rinv * (float)mu[3];
          *(f32x4*)&out[orow + d] = o;
        }
      }
    }
  }
}

extern "C" void kernel_launch(void* const* d_in, const int* in_sizes, int n_in,
                              void* d_out, int out_size, void* d_ws, size_t ws_size,
                              hipStream_t stream) {
  const float* X = (const float*)d_in[0];
  const float* Y = (const float*)d_in[1];
  float* out = (float*)d_out;

  size_t need = (size_t)(2 * XF_ELEMS + 2 * XT_ELEMS) * sizeof(f16);  // ~83 MB
  if (ws_size < need) return;

  f16* Xf = (f16*)d_ws;
  f16* Yf = Xf + XF_ELEMS;
  f16* XT = Yf + XF_ELEMS;
  f16* YT = XT + XT_ELEMS;

  prep_kernel<<<dim3(65, 11, 32), 256, 0, stream>>>(X, Y, Xf, Yf, XT, YT);
  attn_kernel<<<dim3(512), 512, 0, stream>>>(Xf, Yf, XT, YT, out);
}